// Round 12
// baseline (430.725 us; speedup 1.0000x reference)
//
#include <hip/hip_runtime.h>
#include <math.h>

#define G_N 2048
#define CCH 256
#define PSTR 12   // {u,v,A,B,C,op,pthr,gid, rx,ry, pad,pad}
#define NBLK 1024
#define WC (64 * 64 * 9)

typedef short bhalf8 __attribute__((ext_vector_type(8)));
typedef float f32x4 __attribute__((ext_vector_type(4)));
typedef unsigned short u16;

__device__ __forceinline__ u16 f2bf(float f) {
    unsigned u = __float_as_uint(f);
    unsigned r = (u + 0x7fffu + ((u >> 16) & 1u)) >> 16;
    return (u16)r;
}
__device__ __forceinline__ float b2f(u16 h) {
    return __uint_as_float((unsigned)h << 16);
}

// Coherent stores (agent scope -> sc0 sc1: write past L2 to the memory-side
// IC). Consumers use NORMAL cached loads (write-once -> barrier -> first-touch
// read pattern, HW-validated r9/r10). "16B" = two adjacent 8B coherent stores
// (per-lane contiguous; wave emits a contiguous 1KB burst).
__device__ __forceinline__ void chstore8u(void* p, unsigned long long u) {
    __hip_atomic_store((unsigned long long*)p, u,
                       __ATOMIC_RELAXED, __HIP_MEMORY_SCOPE_AGENT);
}
__device__ __forceinline__ void chstore16(void* p, uint4 v) {
    union { uint2 d; unsigned long long u; } a, b;
    a.d = (uint2){v.x, v.y};
    b.d = (uint2){v.z, v.w};
    chstore8u(p, a.u);
    chstore8u((char*)p + 8, b.u);
}
__device__ __forceinline__ void cstore8(float* p, float a, float b) {
    union { unsigned long long u; float f[2]; } x;
    x.f[0] = a; x.f[1] = b;
    chstore8u(p, x.u);
}
__device__ __forceinline__ float cload(const float* p) {
    return __hip_atomic_load(p, __ATOMIC_RELAXED, __HIP_MEMORY_SCOPE_AGENT);
}
__device__ __forceinline__ int iload(const int* p) {
    return __hip_atomic_load(p, __ATOMIC_RELAXED, __HIP_MEMORY_SCOPE_AGENT);
}

// Fence-free grid barrier (validated r6-r10), s_sleep(16) backoff.
__device__ __forceinline__ void gbar(int* leaf, int* root, int* flag, int phase) {
    asm volatile("s_waitcnt vmcnt(0) lgkmcnt(0)" ::: "memory");
    __syncthreads();
    if (threadIdx.x == 0) {
        int g = blockIdx.x >> 5;
        int old = atomicAdd(&leaf[g * 16], 1);
        if ((old & 31) == 31) {
            int o2 = atomicAdd(root, 1);
            if ((o2 & 31) == 31)
                __hip_atomic_store(flag, phase, __ATOMIC_RELAXED,
                                   __HIP_MEMORY_SCOPE_AGENT);
        }
        while (__hip_atomic_load(flag, __ATOMIC_RELAXED,
                                 __HIP_MEMORY_SCOPE_AGENT) < phase)
            __builtin_amdgcn_s_sleep(16);
    }
    __syncthreads();
    asm volatile("" ::: "memory");
}

// Depth-3 pipelined K-loop (72 MFMAs over 18 (tap,chunk) pairs), stride-10 LDS.
#define KLOOP3(WPTR, LDSPTR, SY, SX, ACC)                                      \
    {                                                                          \
        const bhalf8* wp8_ = (const bhalf8*)(WPTR);                            \
        bhalf8 A0_[3], A1_[3], A2_[3], A3_[3], Bv_[3];                         \
        _Pragma("unroll")                                                      \
        for (int i_ = 0; i_ < 3; ++i_) {                                       \
            A0_[i_] = wp8_[(i_ * 4 + 0) * 64 + lane];                          \
            A1_[i_] = wp8_[(i_ * 4 + 1) * 64 + lane];                          \
            A2_[i_] = wp8_[(i_ * 4 + 2) * 64 + lane];                          \
            A3_[i_] = wp8_[(i_ * 4 + 3) * 64 + lane];                          \
            int tap_ = i_ >> 1, ch_ = i_ & 1;                                  \
            int dy_ = tap_ / 3, dx_ = tap_ - dy_ * 3;                          \
            Bv_[i_] = *(const bhalf8*)&(LDSPTR)[(((SY) + dy_) * 10 + (SX) + dx_) * 72 + ch_ * 32 + q * 8]; \
        }                                                                      \
        _Pragma("unroll")                                                      \
        for (int p_ = 0; p_ < 18; ++p_) {                                      \
            int sl_ = p_ % 3;                                                  \
            ACC[0] = __builtin_amdgcn_mfma_f32_16x16x32_bf16(A0_[sl_], Bv_[sl_], ACC[0], 0, 0, 0); \
            ACC[1] = __builtin_amdgcn_mfma_f32_16x16x32_bf16(A1_[sl_], Bv_[sl_], ACC[1], 0, 0, 0); \
            ACC[2] = __builtin_amdgcn_mfma_f32_16x16x32_bf16(A2_[sl_], Bv_[sl_], ACC[2], 0, 0, 0); \
            ACC[3] = __builtin_amdgcn_mfma_f32_16x16x32_bf16(A3_[sl_], Bv_[sl_], ACC[3], 0, 0, 0); \
            int pn_ = p_ + 3;                                                  \
            if (pn_ < 18) {                                                    \
                A0_[sl_] = wp8_[(pn_ * 4 + 0) * 64 + lane];                    \
                A1_[sl_] = wp8_[(pn_ * 4 + 1) * 64 + lane];                    \
                A2_[sl_] = wp8_[(pn_ * 4 + 2) * 64 + lane];                    \
                A3_[sl_] = wp8_[(pn_ * 4 + 3) * 64 + lane];                    \
                int tap_ = pn_ >> 1, ch_ = pn_ & 1;                            \
                int dy_ = tap_ / 3, dx_ = tap_ - dy_ * 3;                      \
                Bv_[sl_] = *(const bhalf8*)&(LDSPTR)[(((SY) + dy_) * 10 + (SX) + dx_) * 72 + ch_ * 32 + q * 8]; \
            }                                                                  \
        }                                                                      \
    }

// ---------------------------------------------------------------------------
// Render one 8x8 tile. Wave w owns channels [w*16,w*16+16); lane = pixel.
// Params slot = gaussian id; culled slots carry rx=ry=-1 (bbox always fails).
// ---------------------------------------------------------------------------
__device__ __forceinline__ void render_tile(
    int unit, const float* __restrict__ params,
    const float* __restrict__ feats, u16* __restrict__ out0,
    u16* __restrict__ out1, char* smem)
{
    int s = (unit < 169) ? 0 : 1;
    int t = (s == 0) ? unit : unit - 169;
    int tw = (s == 0) ? 13 : 25;
    int bxx = t % tw, byy = t / tw;
    int H = 100 << s;
    const float* P = params + s * G_N * PSTR;
    u16* out = s ? out1 : out0;

    float* raw = (float*)smem;
    float* cmp = raw + CCH * PSTR;
    int* s_wsum = (int*)(smem + 24576);

    int tid = threadIdx.x;
    int w = tid >> 6, lane = tid & 63;
    int x0 = bxx * 8, y0 = byy * 8;
    int px = x0 + (lane & 7), py = y0 + (lane >> 3);
    bool active = (px < H) && (py < H);
    float fx = (float)px, fy = (float)py;
    float tx0 = (float)x0, tx1 = (float)min(H - 1, x0 + 7);
    float ty0 = (float)y0, ty1 = (float)min(H - 1, y0 + 7);

    f32x4 acc[4];
#pragma unroll
    for (int k = 0; k < 4; ++k) acc[k] = (f32x4){0.f, 0.f, 0.f, 0.f};
    float T = 1.f;

    for (int base = 0; base < G_N; base += CCH) {
        int anyalive = __syncthreads_or((int)(active && T > 1e-6f));
        if (!anyalive) break;
        for (int i = tid; i < CCH * 3; i += 256)
            ((float4*)raw)[i] = ((const float4*)(P + base * PSTR))[i];
        __syncthreads();
        float u = raw[tid * PSTR + 0], v = raw[tid * PSTR + 1];
        float rx = raw[tid * PSTR + 8], ry = raw[tid * PSTR + 9];
        bool pass = (u + rx >= tx0) && (u - rx <= tx1) &&
                    (v + ry >= ty0) && (v - ry <= ty1);
        unsigned long long bal = __ballot(pass);
        int prefix = __popcll(bal & ((1ull << lane) - 1ull));
        if (lane == 0) s_wsum[w] = __popcll(bal);
        __syncthreads();
        int woff = 0;
        for (int k = 0; k < 4; ++k) if (k < w) woff += s_wsum[k];
        if (pass) {
            float4* dst = (float4*)(cmp + (woff + prefix) * PSTR);
            const float4* src = (const float4*)(raw + tid * PSTR);
            dst[0] = src[0]; dst[1] = src[1]; dst[2] = src[2];
        }
        __syncthreads();
        int nc = s_wsum[0] + s_wsum[1] + s_wsum[2] + s_wsum[3];
        if (active && T > 1e-6f) {
            for (int j = 0; j < nc; ++j) {
                float4 q0 = *(const float4*)(cmp + j * PSTR);
                float4 q1 = *(const float4*)(cmp + j * PSTR + 4);
                float dx = q0.x - fx, dy = q0.y - fy;
                float power = -0.5f * (q0.z * dx * dx + q1.x * dy * dy) - q0.w * dx * dy;
                if (power <= 0.f && power >= q1.z) {
                    float alpha = fminf(q1.y * __expf(power), 0.99f);
                    float wgt = alpha * T;
                    const f32x4* f4 = (const f32x4*)(feats + __float_as_int(q1.w) * 64) + w * 4;
#pragma unroll
                    for (int k = 0; k < 4; ++k) {
                        f32x4 fv = f4[k];
                        acc[k][0] = fmaf(wgt, fv[0], acc[k][0]);
                        acc[k][1] = fmaf(wgt, fv[1], acc[k][1]);
                        acc[k][2] = fmaf(wgt, fv[2], acc[k][2]);
                        acc[k][3] = fmaf(wgt, fv[3], acc[k][3]);
                    }
                    T *= (1.f - alpha);
                }
            }
        }
    }

    __syncthreads();
    float* shf = (float*)smem;   // 64*68 f32 (raw/cmp dead)
#pragma unroll
    for (int k = 0; k < 4; ++k)
        *(float4*)&shf[lane * 68 + w * 16 + k * 4] =
            (float4){acc[k][0], acc[k][1], acc[k][2], acc[k][3]};
    __syncthreads();
    for (int j = tid; j < 512; j += 256) {
        int lp = j >> 3, c8 = (j & 7) * 8;
        int gy = y0 + (lp >> 3), gx = x0 + (lp & 7);
        if (gy < H && gx < H) {
            float4 va = *(float4*)&shf[lp * 68 + c8];
            float4 vb = *(float4*)&shf[lp * 68 + c8 + 4];
            union { u16 s[8]; uint4 u; } pk;
            pk.s[0] = f2bf(va.x); pk.s[1] = f2bf(va.y);
            pk.s[2] = f2bf(va.z); pk.s[3] = f2bf(va.w);
            pk.s[4] = f2bf(vb.x); pk.s[5] = f2bf(vb.y);
            pk.s[6] = f2bf(vb.z); pk.s[7] = f2bf(vb.w);
            chstore16(&out[((gy * H + gx) << 6) + c8], pk.u);
        }
    }
}

// ---------------------------------------------------------------------------
// MFMA conv3x3 tile (8x8 px x 64 oc). Cached loads, coherent bounce stores,
// depth-3 pipelined K-loop.
// ---------------------------------------------------------------------------
__device__ __forceinline__ void conv_tile(
    int bx, int H, const u16* __restrict__ in, const u16* __restrict__ wp,
    const float* __restrict__ bev, u16* __restrict__ outb,
    int ups, int dostats, float* __restrict__ sacc, char* smem)
{
    u16* xlds = (u16*)smem;                      // 100*72*2 = 14400 B
    u16* fin  = (u16*)(smem + 14400);            // 64*72*2 = 9216 B (ups only)
    float* red = (float*)(smem + 25600);         // 512 f

    int tid = threadIdx.x;
    int gw = (H + 7) >> 3;
    int by = bx / gw, bxx = bx - by * gw;
    int y0 = by * 8, x0 = bxx * 8;
    int w = tid >> 6, lane = tid & 63;
    int n = lane & 15, q = lane >> 4;
    int Hh = H >> 1;
    int oy = (y0 >> 1) - 2, ox = (x0 >> 1) - 2;

    if (ups) {
        for (int i = tid; i < 512; i += 256) {
            int px = i >> 3, c8 = (i & 7) * 8;
            int iy = px >> 3, ix = px & 7;
            int gyi = oy + iy, gxi = ox + ix;
            uint4 v = {0, 0, 0, 0};
            if (gyi >= 0 && gyi < Hh && gxi >= 0 && gxi < Hh)
                v = *(const uint4*)&in[((gyi * Hh + gxi) << 6) + c8];
            *(uint4*)&fin[px * 72 + c8] = v;
        }
        __syncthreads();
        for (int i = tid; i < 1600; i += 256) {
            int px = i >> 4, c4 = (i & 15) * 4;
            int yy = px / 10, xx = px - yy * 10;
            int gy = y0 - 1 + yy, gx = x0 - 1 + xx;
            ushort4 v = {0, 0, 0, 0};
            if (gy >= 0 && gy < H && gx >= 0 && gx < H) {
                int yi = gy >> 1, xi = gx >> 1;
                int yb = (gy & 1) ? min(yi + 1, Hh - 1) : max(yi - 1, 0);
                int xb = (gx & 1) ? min(xi + 1, Hh - 1) : max(xi - 1, 0);
                int t0 = yi - oy, t1 = xi - ox, t2 = yb - oy, t3 = xb - ox;
                ushort4 f00 = *(const ushort4*)&fin[(t0 * 8 + t1) * 72 + c4];
                ushort4 f01 = *(const ushort4*)&fin[(t0 * 8 + t3) * 72 + c4];
                ushort4 f10 = *(const ushort4*)&fin[(t2 * 8 + t1) * 72 + c4];
                ushort4 f11 = *(const ushort4*)&fin[(t2 * 8 + t3) * 72 + c4];
                v.x = f2bf(0.5625f * b2f(f00.x) + 0.1875f * (b2f(f01.x) + b2f(f10.x)) + 0.0625f * b2f(f11.x));
                v.y = f2bf(0.5625f * b2f(f00.y) + 0.1875f * (b2f(f01.y) + b2f(f10.y)) + 0.0625f * b2f(f11.y));
                v.z = f2bf(0.5625f * b2f(f00.z) + 0.1875f * (b2f(f01.z) + b2f(f10.z)) + 0.0625f * b2f(f11.z));
                v.w = f2bf(0.5625f * b2f(f00.w) + 0.1875f * (b2f(f01.w) + b2f(f10.w)) + 0.0625f * b2f(f11.w));
            }
            *(ushort4*)&xlds[px * 72 + c4] = v;
        }
    } else {
        for (int i = tid; i < 800; i += 256) {
            int px = i >> 3, c8 = (i & 7) * 8;
            int yy = px / 10, xx = px - yy * 10;
            int gy = y0 - 1 + yy, gx = x0 - 1 + xx;
            uint4 v = {0, 0, 0, 0};
            if (gy >= 0 && gy < H && gx >= 0 && gx < H)
                v = *(const uint4*)&in[((gy * H + gx) << 6) + c8];
            *(uint4*)&xlds[px * 72 + c8] = v;
        }
    }
    __syncthreads();

    f32x4 acc[4];
#pragma unroll
    for (int m = 0; m < 4; ++m) acc[m] = (f32x4){0.f, 0.f, 0.f, 0.f};
    int sy = 2 * w + (n >> 3), sx = n & 7;
    KLOOP3(wp, xlds, sy, sx, acc);

    int gy = y0 + sy, gx = x0 + sx;
    bool ok = (gy < H) && (gx < H);
    int base = ok ? ((gy * H + gx) << 6) : 0;
    ushort4 ov[4];
#pragma unroll
    for (int m = 0; m < 4; ++m) {
        int oc0 = m * 16 + q * 4;
        float v0 = acc[m][0], v1 = acc[m][1], v2 = acc[m][2], v3 = acc[m][3];
        if (bev && ok) {
            float4 av = *(const float4*)&bev[base + oc0];
            v0 += av.x; v1 += av.y; v2 += av.z; v3 += av.w;
        }
        ov[m] = (ushort4){ f2bf(v0), f2bf(v1), f2bf(v2), f2bf(v3) };
    }
    __syncthreads();
    int lp = sy * 8 + sx;
#pragma unroll
    for (int m = 0; m < 4; ++m)
        *(ushort4*)&xlds[lp * 72 + m * 16 + q * 4] = ov[m];
    __syncthreads();
    for (int j = tid; j < 512; j += 256) {
        int pp = j >> 3, c8 = (j & 7) * 8;
        int gy2 = y0 + (pp >> 3), gx2 = x0 + (pp & 7);
        if (gy2 < H && gx2 < H) {
            uint4 v = *(uint4*)&xlds[pp * 72 + c8];
            chstore16(&outb[((gy2 * H + gx2) << 6) + c8], v);
        }
    }

    if (dostats) {
#pragma unroll
        for (int m = 0; m < 4; ++m)
#pragma unroll
            for (int r = 0; r < 4; ++r) {
                float v = acc[m][r];
                float s = v, s2 = v * v;
#pragma unroll
                for (int d = 1; d < 16; d <<= 1) {
                    s += __shfl_xor(s, d, 64);
                    s2 += __shfl_xor(s2, d, 64);
                }
                if (n == 0) {
                    int oc = m * 16 + q * 4 + r;
                    red[w * 128 + oc] = s;
                    red[w * 128 + 64 + oc] = s2;
                }
            }
        __syncthreads();
        if (tid < 128) {
            float t = red[tid] + red[128 + tid] + red[256 + tid] + red[384 + tid];
            atomicAdd(&sacc[tid], t);
        }
    }
}

// ---------------------------------------------------------------------------
// FUSED basic block: out = relu(x + conv2(relu(conv1(x)))).
// Depth-3 pipelined K-loops; coherent bounce epilogue (non-final).
// ---------------------------------------------------------------------------
__device__ __forceinline__ void bb_tile(
    int bx, int H, const u16* __restrict__ in,
    const u16* __restrict__ wp1, const u16* __restrict__ wp2,
    u16* __restrict__ outb, float* __restrict__ outf, int final_,
    int nrm, const u16* __restrict__ nskip, const float* __restrict__ sraw,
    char* smem)
{
    u16* xin  = (u16*)smem;              // 144*72*2 = 20736 B
    u16* ilds = (u16*)(smem + 20736);    // 100*72*2 = 14400 B
    float* nm = (float*)(smem + 35136);  // 64
    float* nr = nm + 64;                 // 64

    int tid = threadIdx.x;
    int gw = (H + 7) >> 3;
    int by = bx / gw, bxx = bx - by * gw;
    int y0 = by * 8, x0 = bxx * 8;
    int w = tid >> 6, lane = tid & 63;
    int n = lane & 15, q = lane >> 4;

    if (nrm) {
        if (tid < 64) {
            float s = cload(&sraw[tid]), s2 = cload(&sraw[64 + tid]);
            float mean = s * (1.f / 40000.f);
            float var = s2 * (1.f / 40000.f) - mean * mean;
            nm[tid] = mean;
            nr[tid] = rsqrtf(var + 1e-5f);
        }
        __syncthreads();
        for (int i = tid; i < 2304; i += 256) {
            int px = i >> 4, c4 = (i & 15) * 4;
            int yy = px / 12, xx = px - yy * 12;
            int gy = y0 - 2 + yy, gx = x0 - 2 + xx;
            ushort4 v = {0, 0, 0, 0};
            if (gy >= 0 && gy < H && gx >= 0 && gx < H) {
                int off = ((gy * H + gx) << 6) + c4;
                ushort4 a = *(const ushort4*)&in[off];
                ushort4 b = *(const ushort4*)&nskip[off];
                v.x = f2bf((b2f(a.x) - nm[c4 + 0]) * nr[c4 + 0] + b2f(b.x));
                v.y = f2bf((b2f(a.y) - nm[c4 + 1]) * nr[c4 + 1] + b2f(b.y));
                v.z = f2bf((b2f(a.z) - nm[c4 + 2]) * nr[c4 + 2] + b2f(b.z));
                v.w = f2bf((b2f(a.w) - nm[c4 + 3]) * nr[c4 + 3] + b2f(b.w));
            }
            *(ushort4*)&xin[px * 72 + c4] = v;
        }
    } else {
        for (int i = tid; i < 1152; i += 256) {
            int px = i >> 3, c8 = (i & 7) * 8;
            int yy = px / 12, xx = px - yy * 12;
            int gy = y0 - 2 + yy, gx = x0 - 2 + xx;
            uint4 v = {0, 0, 0, 0};
            if (gy >= 0 && gy < H && gx >= 0 && gx < H)
                v = *(const uint4*)&in[((gy * H + gx) << 6) + c8];
            *(uint4*)&xin[px * 72 + c8] = v;
        }
    }
    __syncthreads();

    // conv1: 10x10 intermediate, 2 rounds of 4 wave-tiles (stride-12 input)
#pragma unroll 1
    for (int r = 0; r < 2; ++r) {
        int t = w + 4 * r;
        int px = t * 16 + n;
        bool val = px < 100;
        int pc = val ? px : 0;
        int yy = pc / 10, xx = pc - yy * 10;

        f32x4 acc1[4];
#pragma unroll
        for (int m = 0; m < 4; ++m) acc1[m] = (f32x4){0.f, 0.f, 0.f, 0.f};

        {
            const bhalf8* wp8_ = (const bhalf8*)wp1;
            bhalf8 A0_[3], A1_[3], A2_[3], A3_[3], Bv_[3];
#pragma unroll
            for (int i_ = 0; i_ < 3; ++i_) {
                A0_[i_] = wp8_[(i_ * 4 + 0) * 64 + lane];
                A1_[i_] = wp8_[(i_ * 4 + 1) * 64 + lane];
                A2_[i_] = wp8_[(i_ * 4 + 2) * 64 + lane];
                A3_[i_] = wp8_[(i_ * 4 + 3) * 64 + lane];
                int tap_ = i_ >> 1, ch_ = i_ & 1;
                int dy_ = tap_ / 3, dx_ = tap_ - dy_ * 3;
                Bv_[i_] = *(const bhalf8*)&xin[((yy + dy_) * 12 + xx + dx_) * 72 + ch_ * 32 + q * 8];
            }
#pragma unroll
            for (int p_ = 0; p_ < 18; ++p_) {
                int sl_ = p_ % 3;
                acc1[0] = __builtin_amdgcn_mfma_f32_16x16x32_bf16(A0_[sl_], Bv_[sl_], acc1[0], 0, 0, 0);
                acc1[1] = __builtin_amdgcn_mfma_f32_16x16x32_bf16(A1_[sl_], Bv_[sl_], acc1[1], 0, 0, 0);
                acc1[2] = __builtin_amdgcn_mfma_f32_16x16x32_bf16(A2_[sl_], Bv_[sl_], acc1[2], 0, 0, 0);
                acc1[3] = __builtin_amdgcn_mfma_f32_16x16x32_bf16(A3_[sl_], Bv_[sl_], acc1[3], 0, 0, 0);
                int pn_ = p_ + 3;
                if (pn_ < 18) {
                    A0_[sl_] = wp8_[(pn_ * 4 + 0) * 64 + lane];
                    A1_[sl_] = wp8_[(pn_ * 4 + 1) * 64 + lane];
                    A2_[sl_] = wp8_[(pn_ * 4 + 2) * 64 + lane];
                    A3_[sl_] = wp8_[(pn_ * 4 + 3) * 64 + lane];
                    int tap_ = pn_ >> 1, ch_ = pn_ & 1;
                    int dy_ = tap_ / 3, dx_ = tap_ - dy_ * 3;
                    Bv_[sl_] = *(const bhalf8*)&xin[((yy + dy_) * 12 + xx + dx_) * 72 + ch_ * 32 + q * 8];
                }
            }
        }

        int iy = y0 - 1 + yy, ix = x0 - 1 + xx;
        bool ok1 = val && iy >= 0 && iy < H && ix >= 0 && ix < H;
        if (val) {
#pragma unroll
            for (int m = 0; m < 4; ++m) {
                ushort4 o = {0, 0, 0, 0};
                if (ok1) {
                    o.x = f2bf(fmaxf(acc1[m][0], 0.f));
                    o.y = f2bf(fmaxf(acc1[m][1], 0.f));
                    o.z = f2bf(fmaxf(acc1[m][2], 0.f));
                    o.w = f2bf(fmaxf(acc1[m][3], 0.f));
                }
                *(ushort4*)&ilds[px * 72 + m * 16 + q * 4] = o;
            }
        }
    }
    __syncthreads();

    // conv2: 8x8 output from ilds
    f32x4 acc[4];
#pragma unroll
    for (int m = 0; m < 4; ++m) acc[m] = (f32x4){0.f, 0.f, 0.f, 0.f};
    int sy = 2 * w + (n >> 3), sx = n & 7;
    KLOOP3(wp2, ilds, sy, sx, acc);

    int gy = y0 + sy, gx = x0 + sx;
    bool ok = (gy < H) && (gx < H);
    ushort4 ov[4];
    float vf[4][4];
#pragma unroll
    for (int m = 0; m < 4; ++m) {
        int oc0 = m * 16 + q * 4;
        ushort4 xr = *(const ushort4*)&xin[((sy + 2) * 12 + sx + 2) * 72 + oc0];
        vf[m][0] = fmaxf(acc[m][0] + b2f(xr.x), 0.f);
        vf[m][1] = fmaxf(acc[m][1] + b2f(xr.y), 0.f);
        vf[m][2] = fmaxf(acc[m][2] + b2f(xr.z), 0.f);
        vf[m][3] = fmaxf(acc[m][3] + b2f(xr.w), 0.f);
        ov[m] = (ushort4){ f2bf(vf[m][0]), f2bf(vf[m][1]), f2bf(vf[m][2]), f2bf(vf[m][3]) };
    }

    if (final_) {
        if (ok) {
            int pix = gy * H + gx;
#pragma unroll
            for (int m = 0; m < 4; ++m) {
                int oc0 = m * 16 + q * 4;
                outf[(oc0 + 0) * H * H + pix] = vf[m][0];
                outf[(oc0 + 1) * H * H + pix] = vf[m][1];
                outf[(oc0 + 2) * H * H + pix] = vf[m][2];
                outf[(oc0 + 3) * H * H + pix] = vf[m][3];
            }
        }
    } else {
        __syncthreads();   // conv2 LDS reads + residual xin reads done
        int lp = sy * 8 + sx;
#pragma unroll
        for (int m = 0; m < 4; ++m)
            *(ushort4*)&xin[lp * 72 + m * 16 + q * 4] = ov[m];
        __syncthreads();
        for (int j = tid; j < 512; j += 256) {
            int pp = j >> 3, c8 = (j & 7) * 8;
            int gy2 = y0 + (pp >> 3), gx2 = x0 + (pp & 7);
            if (gy2 < H && gx2 < H) {
                uint4 v = *(uint4*)&xin[pp * 72 + c8];
                chstore16(&outb[((gy2 * H + gx2) << 6) + c8], v);
            }
        }
    }
}

// ---------------------------------------------------------------------------
// Persistent megakernel: 8 phases, 7 grid barriers.
// ---------------------------------------------------------------------------
__global__ __launch_bounds__(256, 4) void gls_mega(
    const float* __restrict__ feats, const float* __restrict__ bev_emb,
    const float* __restrict__ conv1_w, const float* __restrict__ blk_w,
    const float* __restrict__ up_w, const float* __restrict__ means,
    const float* __restrict__ cov6, const float* __restrict__ opac,
    u16* __restrict__ wprep, float* __restrict__ params, int* __restrict__ cnts,
    u16* __restrict__ R0h, u16* __restrict__ X0h,
    u16* __restrict__ X1h, u16* __restrict__ X2h,
    u16* __restrict__ Qr0h, u16* __restrict__ Sh,
    u16* __restrict__ Uh, u16* __restrict__ Y1h,
    float* __restrict__ out, int* __restrict__ barmem, float* __restrict__ sacc)
{
    __shared__ __align__(16) char smem[36352];
    int bid = blockIdx.x;
    int tid = threadIdx.x;
    int* leaf = barmem;
    int* root = barmem + 512;
    int* flag = barmem + 513;
    int ph = 0;

    // ---- P0: parallel splat precompute (16 blocks) ----
    if (bid < 16) {
        int item = bid * 256 + tid;
        int s = item >> 11, g = item & 2047;
        float mx = means[g * 3 + 0], my = means[g * 3 + 1], mz = means[g * 3 + 2];
        float op = opac[g * 2 + s];
        bool mask = (mx >= -50.f && mx <= 50.f && my >= -50.f && my <= 50.f &&
                     mz >= -4.f && mz <= 4.f && op > 0.05f);
        float Hs = (float)(100 << s), sh = (float)(1 << s);
        float u = 0.f, v = 0.f, A = 0.f, B = 0.f, C = 0.f, pthr = 0.f;
        float rx = -1.f, ry = -1.f;
        if (mask) {
            u = -sh * my + 0.5f * Hs;
            v = -sh * mx + 0.5f * Hs;
            float a = sh * sh * cov6[g * 6 + 3] + 0.3f;
            float c = sh * sh * cov6[g * 6 + 0] + 0.3f;
            float bb = sh * sh * cov6[g * 6 + 1];
            float det = fmaxf(a * c - bb * bb, 1e-8f);
            float t = logf(255.f * op);
            A = c / det; B = -bb / det; C = a / det;
            pthr = -t;
            rx = sqrtf(2.f * t * a); ry = sqrtf(2.f * t * c);
        }
        float* Q = params + (s * G_N + g) * PSTR;
        cstore8(&Q[0], u, v);
        cstore8(&Q[2], A, B);
        cstore8(&Q[4], C, op);
        cstore8(&Q[6], pthr, __int_as_float(g));
        cstore8(&Q[8], rx, ry);
        unsigned long long bal = __ballot(mask);
        if ((tid & 63) == 0) atomicAdd(&cnts[s], __popcll(bal));
    }
    gbar(leaf, root, flag, ++ph);

    // ---- P1: render (0..793) || weight repack (794..991) ----
    if (bid < 794) {
        render_tile(bid, params, feats, R0h, Qr0h, smem);
    } else if (bid < 992) {
        int rb = bid - 794;
        int p = rb % 18, c = rb / 18;
        const float* src;
        if (c == 0) src = conv1_w;
        else if (c <= 4) src = blk_w + (c - 1) * WC;
        else if (c == 5) src = conv1_w + WC;
        else if (c == 6) src = up_w;
        else src = blk_w + (c - 3) * WC;
        int tap = p >> 1;
        int m = tid >> 6, lane = tid & 63;
        int oc = m * 16 + (lane & 15);
        int ci0 = (p & 1) * 32 + (lane >> 4) * 8;
        union { u16 s[8]; uint4 u; } pk;
#pragma unroll
        for (int j = 0; j < 8; ++j)
            pk.s[j] = f2bf(src[(oc * 64 + ci0 + j) * 9 + tap]);
        u16* dst = wprep + ((c * 18 + p) * 4 + m) * 64 * 8 + lane * 8;
        chstore16(dst, pk.u);
    }
    gbar(leaf, root, flag, ++ph);

    // ---- P2: c0 (H100, +bev_emb) ----
    if (bid < 169)
        conv_tile(bid, 100, R0h, wprep + 0 * WC, bev_emb, X0h, 0, 0, nullptr, smem);
    gbar(leaf, root, flag, ++ph);

    // ---- P3: bb1 (H100) || c5 tiles 0..311 ----
    if (bid < 169)
        bb_tile(bid, 100, X0h, wprep + 1 * WC, wprep + 2 * WC, X1h,
                nullptr, 0, 0, nullptr, nullptr, smem);
    else if (bid < 481)
        conv_tile(bid - 169, 200, Qr0h, wprep + 5 * WC, nullptr, Sh, 0, 0, nullptr, smem);
    gbar(leaf, root, flag, ++ph);

    // ---- P4: bb2 (H100) || c5 tiles 312..624 ----
    if (bid < 169)
        bb_tile(bid, 100, X1h, wprep + 3 * WC, wprep + 4 * WC, X2h,
                nullptr, 0, 0, nullptr, nullptr, smem);
    else if (bid < 482)
        conv_tile(312 + bid - 169, 200, Qr0h, wprep + 5 * WC, nullptr, Sh, 0, 0, nullptr, smem);
    gbar(leaf, root, flag, ++ph);

    // ---- P5: upconv (LDS bilinear) + instance-norm stats ----
    if (bid < 625)
        conv_tile(bid, 200, X2h, wprep + 6 * WC, nullptr, Uh, 1, 1, sacc, smem);
    gbar(leaf, root, flag, ++ph);

    // ---- P6: fused bb with instance-norm + skip staging ----
    if (bid < 625)
        bb_tile(bid, 200, Uh, wprep + 7 * WC, wprep + 8 * WC, Y1h,
                nullptr, 0, 1, Sh, sacc, smem);
    gbar(leaf, root, flag, ++ph);

    // ---- P7: fused bb, final epilogue writes d_out (f32 NCHW) ----
    if (bid == 0 && threadIdx.x == 0)
        out[2560000] = (float)(iload(&cnts[0]) + iload(&cnts[1]));
    if (bid < 625)
        bb_tile(bid, 200, Y1h, wprep + 9 * WC, wprep + 10 * WC, nullptr,
                out, 1, 0, nullptr, nullptr, smem);
}

// ---------------------------------------------------------------------------
extern "C" void kernel_launch(void* const* d_in, const int* in_sizes, int n_in,
                              void* d_out, int out_size, void* d_ws, size_t ws_size,
                              hipStream_t stream)
{
    const float* feats   = (const float*)d_in[0];
    const float* means   = (const float*)d_in[1];
    const float* cov6    = (const float*)d_in[2];
    const float* opac    = (const float*)d_in[3];
    const float* bev_emb = (const float*)d_in[4];
    const float* conv1_w = (const float*)d_in[5];
    const float* blk_w   = (const float*)d_in[6];
    const float* up_w    = (const float*)d_in[7];
    float* out = (float*)d_out;
    float* ws = (float*)d_ws;

    float* P      = ws;                          // 49152 floats
    int*   cnts   = (int*)(ws + 49152);          // 2 ints
    int*   barmem = (int*)(ws + 49280);          // 520 ints
    float* sacc   = ws + 49856;                  // 128 floats -> ends 49984
    u16*   wprep  = (u16*)(ws + 50176);          // 11*36864 u16

    u16* R0h  = (u16*)(ws + 262144);             // H100 bf16 HWC
    u16* X0h  = (u16*)(ws + 589824);
    u16* X1h  = (u16*)(ws + 917504);
    u16* X2h  = (u16*)(ws + 1245184);
    u16* Qr0h = (u16*)(ws + 1572864);            // H200 bf16 HWC
    u16* Sh   = (u16*)(ws + 2883584);
    u16* Uh   = (u16*)(ws + 4194304);
    u16* Y1h  = (u16*)(ws + 5505024);

    hipMemsetAsync(cnts, 0, (49984 - 49152) * 4, stream);
    gls_mega<<<NBLK, 256, 0, stream>>>(feats, bev_emb, conv1_w, blk_w, up_w,
                                       means, cov6, opac, wprep, P, cnts,
                                       R0h, X0h, X1h, X2h, Qr0h, Sh, Uh, Y1h,
                                       out, barmem, sacc);
    (void)in_sizes; (void)n_in; (void)out_size; (void)ws_size;
}

// Round 13
// 259.567 us; speedup vs baseline: 1.6594x; 1.6594x over previous
//
#include <hip/hip_runtime.h>
#include <math.h>

#define G_N 2048
#define CCH 256
#define PSTR 12   // {u,v,A,B,C,op,pthr,gid, rx,ry, pad,pad}
#define NBLK 1024
#define WC (64 * 64 * 9)

typedef short bhalf8 __attribute__((ext_vector_type(8)));
typedef float f32x4 __attribute__((ext_vector_type(4)));
typedef unsigned short u16;

__device__ __forceinline__ u16 f2bf(float f) {
    unsigned u = __float_as_uint(f);
    unsigned r = (u + 0x7fffu + ((u >> 16) & 1u)) >> 16;
    return (u16)r;
}
__device__ __forceinline__ float b2f(u16 h) {
    return __uint_as_float((unsigned)h << 16);
}

// Coherent stores (agent scope -> sc0 sc1: write past L2 to the memory-side
// IC). Consumers use NORMAL cached loads: each buffer is write-once-then-read
// with a grid barrier between, L2 is invalidated at kernel start, and the
// first-touch load misses L2 -> fetches fresh IC data. Pattern HW-validated
// in r9/r10. [r12 ERRATA: depth-3 indexed-array K-loop pipelining caused
// scratch spills (FETCH/WRITE +700MB, 1.8x regression) — this is the exact
// r10 best-known-good configuration.]
__device__ __forceinline__ void chstore4(u16* p, ushort4 v) {
    union { unsigned long long u; ushort4 s; } x; x.s = v;
    __hip_atomic_store((unsigned long long*)p, x.u,
                       __ATOMIC_RELAXED, __HIP_MEMORY_SCOPE_AGENT);
}
__device__ __forceinline__ void cstore8(float* p, float a, float b) {
    union { unsigned long long u; float f[2]; } x;
    x.f[0] = a; x.f[1] = b;
    __hip_atomic_store((unsigned long long*)p, x.u,
                       __ATOMIC_RELAXED, __HIP_MEMORY_SCOPE_AGENT);
}
__device__ __forceinline__ float cload(const float* p) {
    return __hip_atomic_load(p, __ATOMIC_RELAXED, __HIP_MEMORY_SCOPE_AGENT);
}
__device__ __forceinline__ int iload(const int* p) {
    return __hip_atomic_load(p, __ATOMIC_RELAXED, __HIP_MEMORY_SCOPE_AGENT);
}

// Fence-free grid barrier (validated r6-r10), s_sleep(16) backoff.
__device__ __forceinline__ void gbar(int* leaf, int* root, int* flag, int phase) {
    asm volatile("s_waitcnt vmcnt(0) lgkmcnt(0)" ::: "memory");
    __syncthreads();
    if (threadIdx.x == 0) {
        int g = blockIdx.x >> 5;
        int old = atomicAdd(&leaf[g * 16], 1);
        if ((old & 31) == 31) {
            int o2 = atomicAdd(root, 1);
            if ((o2 & 31) == 31)
                __hip_atomic_store(flag, phase, __ATOMIC_RELAXED,
                                   __HIP_MEMORY_SCOPE_AGENT);
        }
        while (__hip_atomic_load(flag, __ATOMIC_RELAXED,
                                 __HIP_MEMORY_SCOPE_AGENT) < phase)
            __builtin_amdgcn_s_sleep(16);
    }
    __syncthreads();
    asm volatile("" ::: "memory");
}

// ---------------------------------------------------------------------------
// Render one 8x8 tile. Wave w owns channels [w*16,w*16+16); lane = pixel.
// Params slot = gaussian id; culled slots carry rx=ry=-1 (bbox always fails).
// ---------------------------------------------------------------------------
__device__ __forceinline__ void render_tile(
    int unit, const float* __restrict__ params,
    const float* __restrict__ feats, u16* __restrict__ out0,
    u16* __restrict__ out1, char* smem)
{
    int s = (unit < 169) ? 0 : 1;
    int t = (s == 0) ? unit : unit - 169;
    int tw = (s == 0) ? 13 : 25;
    int bxx = t % tw, byy = t / tw;
    int H = 100 << s;
    const float* P = params + s * G_N * PSTR;
    u16* out = s ? out1 : out0;

    float* raw = (float*)smem;
    float* cmp = raw + CCH * PSTR;
    int* s_wsum = (int*)(smem + 24576);

    int tid = threadIdx.x;
    int w = tid >> 6, lane = tid & 63;
    int x0 = bxx * 8, y0 = byy * 8;
    int px = x0 + (lane & 7), py = y0 + (lane >> 3);
    bool active = (px < H) && (py < H);
    float fx = (float)px, fy = (float)py;
    float tx0 = (float)x0, tx1 = (float)min(H - 1, x0 + 7);
    float ty0 = (float)y0, ty1 = (float)min(H - 1, y0 + 7);

    f32x4 acc[4];
#pragma unroll
    for (int k = 0; k < 4; ++k) acc[k] = (f32x4){0.f, 0.f, 0.f, 0.f};
    float T = 1.f;

    for (int base = 0; base < G_N; base += CCH) {
        int anyalive = __syncthreads_or((int)(active && T > 1e-6f));
        if (!anyalive) break;
        for (int i = tid; i < CCH * 3; i += 256)
            ((float4*)raw)[i] = ((const float4*)(P + base * PSTR))[i];
        __syncthreads();
        float u = raw[tid * PSTR + 0], v = raw[tid * PSTR + 1];
        float rx = raw[tid * PSTR + 8], ry = raw[tid * PSTR + 9];
        bool pass = (u + rx >= tx0) && (u - rx <= tx1) &&
                    (v + ry >= ty0) && (v - ry <= ty1);
        unsigned long long bal = __ballot(pass);
        int prefix = __popcll(bal & ((1ull << lane) - 1ull));
        if (lane == 0) s_wsum[w] = __popcll(bal);
        __syncthreads();
        int woff = 0;
        for (int k = 0; k < 4; ++k) if (k < w) woff += s_wsum[k];
        if (pass) {
            float4* dst = (float4*)(cmp + (woff + prefix) * PSTR);
            const float4* src = (const float4*)(raw + tid * PSTR);
            dst[0] = src[0]; dst[1] = src[1]; dst[2] = src[2];
        }
        __syncthreads();
        int nc = s_wsum[0] + s_wsum[1] + s_wsum[2] + s_wsum[3];
        if (active && T > 1e-6f) {
            for (int j = 0; j < nc; ++j) {
                float4 q0 = *(const float4*)(cmp + j * PSTR);
                float4 q1 = *(const float4*)(cmp + j * PSTR + 4);
                float dx = q0.x - fx, dy = q0.y - fy;
                float power = -0.5f * (q0.z * dx * dx + q1.x * dy * dy) - q0.w * dx * dy;
                if (power <= 0.f && power >= q1.z) {
                    float alpha = fminf(q1.y * __expf(power), 0.99f);
                    float wgt = alpha * T;
                    const f32x4* f4 = (const f32x4*)(feats + __float_as_int(q1.w) * 64) + w * 4;
#pragma unroll
                    for (int k = 0; k < 4; ++k) {
                        f32x4 fv = f4[k];
                        acc[k][0] = fmaf(wgt, fv[0], acc[k][0]);
                        acc[k][1] = fmaf(wgt, fv[1], acc[k][1]);
                        acc[k][2] = fmaf(wgt, fv[2], acc[k][2]);
                        acc[k][3] = fmaf(wgt, fv[3], acc[k][3]);
                    }
                    T *= (1.f - alpha);
                }
            }
        }
    }

    __syncthreads();
    float* shf = (float*)smem;   // 64*68 f32 (raw/cmp dead)
#pragma unroll
    for (int k = 0; k < 4; ++k)
        *(float4*)&shf[lane * 68 + w * 16 + k * 4] =
            (float4){acc[k][0], acc[k][1], acc[k][2], acc[k][3]};
    __syncthreads();
    for (int j = tid; j < 1024; j += 256) {
        int lp = j >> 4, c4 = (j & 15) * 4;
        int gy = y0 + (lp >> 3), gx = x0 + (lp & 7);
        if (gy < H && gx < H) {
            float4 v = *(float4*)&shf[lp * 68 + c4];
            ushort4 o = { f2bf(v.x), f2bf(v.y), f2bf(v.z), f2bf(v.w) };
            chstore4(&out[((gy * H + gx) << 6) + c4], o);
        }
    }
}

// ---------------------------------------------------------------------------
// MFMA conv3x3 tile (8x8 px x 64 oc). Cached loads, coherent stores.
// 1-deep named-variable prefetch (r10 verified; no scratch spill).
// ---------------------------------------------------------------------------
__device__ __forceinline__ void conv_tile(
    int bx, int H, const u16* __restrict__ in, const u16* __restrict__ wp,
    const float* __restrict__ bev, u16* __restrict__ outb,
    int ups, int dostats, float* __restrict__ sacc, char* smem)
{
    u16* xlds = (u16*)smem;                      // 100*72*2 = 14400 B
    u16* fin  = (u16*)(smem + 14400);            // 64*72*2 = 9216 B (ups only)
    float* red = (float*)(smem + 25600);         // 512 f

    int tid = threadIdx.x;
    int gw = (H + 7) >> 3;
    int by = bx / gw, bxx = bx - by * gw;
    int y0 = by * 8, x0 = bxx * 8;
    int w = tid >> 6, lane = tid & 63;
    int n = lane & 15, q = lane >> 4;
    int Hh = H >> 1;
    int oy = (y0 >> 1) - 2, ox = (x0 >> 1) - 2;

    if (ups) {
        for (int i = tid; i < 512; i += 256) {
            int px = i >> 3, c8 = (i & 7) * 8;
            int iy = px >> 3, ix = px & 7;
            int gyi = oy + iy, gxi = ox + ix;
            uint4 v = {0, 0, 0, 0};
            if (gyi >= 0 && gyi < Hh && gxi >= 0 && gxi < Hh)
                v = *(const uint4*)&in[((gyi * Hh + gxi) << 6) + c8];
            *(uint4*)&fin[px * 72 + c8] = v;
        }
        __syncthreads();
        for (int i = tid; i < 1600; i += 256) {
            int px = i >> 4, c4 = (i & 15) * 4;
            int yy = px / 10, xx = px - yy * 10;
            int gy = y0 - 1 + yy, gx = x0 - 1 + xx;
            ushort4 v = {0, 0, 0, 0};
            if (gy >= 0 && gy < H && gx >= 0 && gx < H) {
                int yi = gy >> 1, xi = gx >> 1;
                int yb = (gy & 1) ? min(yi + 1, Hh - 1) : max(yi - 1, 0);
                int xb = (gx & 1) ? min(xi + 1, Hh - 1) : max(xi - 1, 0);
                int t0 = yi - oy, t1 = xi - ox, t2 = yb - oy, t3 = xb - ox;
                ushort4 f00 = *(const ushort4*)&fin[(t0 * 8 + t1) * 72 + c4];
                ushort4 f01 = *(const ushort4*)&fin[(t0 * 8 + t3) * 72 + c4];
                ushort4 f10 = *(const ushort4*)&fin[(t2 * 8 + t1) * 72 + c4];
                ushort4 f11 = *(const ushort4*)&fin[(t2 * 8 + t3) * 72 + c4];
                v.x = f2bf(0.5625f * b2f(f00.x) + 0.1875f * (b2f(f01.x) + b2f(f10.x)) + 0.0625f * b2f(f11.x));
                v.y = f2bf(0.5625f * b2f(f00.y) + 0.1875f * (b2f(f01.y) + b2f(f10.y)) + 0.0625f * b2f(f11.y));
                v.z = f2bf(0.5625f * b2f(f00.z) + 0.1875f * (b2f(f01.z) + b2f(f10.z)) + 0.0625f * b2f(f11.z));
                v.w = f2bf(0.5625f * b2f(f00.w) + 0.1875f * (b2f(f01.w) + b2f(f10.w)) + 0.0625f * b2f(f11.w));
            }
            *(ushort4*)&xlds[px * 72 + c4] = v;
        }
    } else {
        for (int i = tid; i < 800; i += 256) {
            int px = i >> 3, c8 = (i & 7) * 8;
            int yy = px / 10, xx = px - yy * 10;
            int gy = y0 - 1 + yy, gx = x0 - 1 + xx;
            uint4 v = {0, 0, 0, 0};
            if (gy >= 0 && gy < H && gx >= 0 && gx < H)
                v = *(const uint4*)&in[((gy * H + gx) << 6) + c8];
            *(uint4*)&xlds[px * 72 + c8] = v;
        }
    }
    __syncthreads();

    f32x4 acc[4];
#pragma unroll
    for (int m = 0; m < 4; ++m) acc[m] = (f32x4){0.f, 0.f, 0.f, 0.f};
    const bhalf8* wp8 = (const bhalf8*)wp;
    int sy = 2 * w + (n >> 3), sx = n & 7;

    bhalf8 a0 = wp8[0 * 64 + lane];
    bhalf8 a1 = wp8[1 * 64 + lane];
    bhalf8 a2 = wp8[2 * 64 + lane];
    bhalf8 a3 = wp8[3 * 64 + lane];
    bhalf8 bb = *(const bhalf8*)&xlds[(sy * 10 + sx) * 72 + q * 8];

#pragma unroll 1
    for (int p = 0; p < 18; ++p) {
        bhalf8 na0, na1, na2, na3, nbb;
        if (p < 17) {
            int pn = p + 1;
            na0 = wp8[(pn * 4 + 0) * 64 + lane];
            na1 = wp8[(pn * 4 + 1) * 64 + lane];
            na2 = wp8[(pn * 4 + 2) * 64 + lane];
            na3 = wp8[(pn * 4 + 3) * 64 + lane];
            int tap = pn >> 1, ch = pn & 1;
            int dy = tap / 3, dx = tap - dy * 3;
            nbb = *(const bhalf8*)&xlds[((sy + dy) * 10 + sx + dx) * 72 + ch * 32 + q * 8];
        }
        acc[0] = __builtin_amdgcn_mfma_f32_16x16x32_bf16(a0, bb, acc[0], 0, 0, 0);
        acc[1] = __builtin_amdgcn_mfma_f32_16x16x32_bf16(a1, bb, acc[1], 0, 0, 0);
        acc[2] = __builtin_amdgcn_mfma_f32_16x16x32_bf16(a2, bb, acc[2], 0, 0, 0);
        acc[3] = __builtin_amdgcn_mfma_f32_16x16x32_bf16(a3, bb, acc[3], 0, 0, 0);
        a0 = na0; a1 = na1; a2 = na2; a3 = na3; bb = nbb;
    }

    int gy = y0 + sy, gx = x0 + sx;
    if (gy < H && gx < H) {
        int base = (gy * H + gx) << 6;
#pragma unroll
        for (int m = 0; m < 4; ++m) {
            int oc0 = m * 16 + q * 4;
            float v0 = acc[m][0], v1 = acc[m][1], v2 = acc[m][2], v3 = acc[m][3];
            if (bev) {
                float4 av = *(const float4*)&bev[base + oc0];
                v0 += av.x; v1 += av.y; v2 += av.z; v3 += av.w;
            }
            ushort4 o = { f2bf(v0), f2bf(v1), f2bf(v2), f2bf(v3) };
            chstore4(&outb[base + oc0], o);
        }
    }

    if (dostats) {
#pragma unroll
        for (int m = 0; m < 4; ++m)
#pragma unroll
            for (int r = 0; r < 4; ++r) {
                float v = acc[m][r];
                float s = v, s2 = v * v;
#pragma unroll
                for (int d = 1; d < 16; d <<= 1) {
                    s += __shfl_xor(s, d, 64);
                    s2 += __shfl_xor(s2, d, 64);
                }
                if (n == 0) {
                    int oc = m * 16 + q * 4 + r;
                    red[w * 128 + oc] = s;
                    red[w * 128 + 64 + oc] = s2;
                }
            }
        __syncthreads();
        if (tid < 128) {
            float t = red[tid] + red[128 + tid] + red[256 + tid] + red[384 + tid];
            atomicAdd(&sacc[tid], t);
        }
    }
}

// ---------------------------------------------------------------------------
// FUSED basic block: out = relu(x + conv2(relu(conv1(x)))). Cached loads,
// coherent stores. nrm: x = instnorm(in)+nskip at staging. final_: f32 NCHW.
// ---------------------------------------------------------------------------
__device__ __forceinline__ void bb_tile(
    int bx, int H, const u16* __restrict__ in,
    const u16* __restrict__ wp1, const u16* __restrict__ wp2,
    u16* __restrict__ outb, float* __restrict__ outf, int final_,
    int nrm, const u16* __restrict__ nskip, const float* __restrict__ sraw,
    char* smem)
{
    u16* xin  = (u16*)smem;              // 144*72*2 = 20736 B
    u16* ilds = (u16*)(smem + 20736);    // 100*72*2 = 14400 B
    float* nm = (float*)(smem + 35136);  // 64
    float* nr = nm + 64;                 // 64

    int tid = threadIdx.x;
    int gw = (H + 7) >> 3;
    int by = bx / gw, bxx = bx - by * gw;
    int y0 = by * 8, x0 = bxx * 8;
    int w = tid >> 6, lane = tid & 63;
    int n = lane & 15, q = lane >> 4;

    if (nrm) {
        if (tid < 64) {
            float s = cload(&sraw[tid]), s2 = cload(&sraw[64 + tid]);
            float mean = s * (1.f / 40000.f);
            float var = s2 * (1.f / 40000.f) - mean * mean;
            nm[tid] = mean;
            nr[tid] = rsqrtf(var + 1e-5f);
        }
        __syncthreads();
        for (int i = tid; i < 2304; i += 256) {
            int px = i >> 4, c4 = (i & 15) * 4;
            int yy = px / 12, xx = px - yy * 12;
            int gy = y0 - 2 + yy, gx = x0 - 2 + xx;
            ushort4 v = {0, 0, 0, 0};
            if (gy >= 0 && gy < H && gx >= 0 && gx < H) {
                int off = ((gy * H + gx) << 6) + c4;
                ushort4 a = *(const ushort4*)&in[off];
                ushort4 b = *(const ushort4*)&nskip[off];
                v.x = f2bf((b2f(a.x) - nm[c4 + 0]) * nr[c4 + 0] + b2f(b.x));
                v.y = f2bf((b2f(a.y) - nm[c4 + 1]) * nr[c4 + 1] + b2f(b.y));
                v.z = f2bf((b2f(a.z) - nm[c4 + 2]) * nr[c4 + 2] + b2f(b.z));
                v.w = f2bf((b2f(a.w) - nm[c4 + 3]) * nr[c4 + 3] + b2f(b.w));
            }
            *(ushort4*)&xin[px * 72 + c4] = v;
        }
    } else {
        for (int i = tid; i < 1152; i += 256) {
            int px = i >> 3, c8 = (i & 7) * 8;
            int yy = px / 12, xx = px - yy * 12;
            int gy = y0 - 2 + yy, gx = x0 - 2 + xx;
            uint4 v = {0, 0, 0, 0};
            if (gy >= 0 && gy < H && gx >= 0 && gx < H)
                v = *(const uint4*)&in[((gy * H + gx) << 6) + c8];
            *(uint4*)&xin[px * 72 + c8] = v;
        }
    }
    __syncthreads();

    // conv1: 10x10 intermediate, 2 rounds of 4 wave-tiles (stride-12 input)
#pragma unroll 1
    for (int r = 0; r < 2; ++r) {
        int t = w + 4 * r;
        int px = t * 16 + n;
        bool val = px < 100;
        int pc = val ? px : 0;
        int yy = pc / 10, xx = pc - yy * 10;

        f32x4 acc1[4];
#pragma unroll
        for (int m = 0; m < 4; ++m) acc1[m] = (f32x4){0.f, 0.f, 0.f, 0.f};

        {
            const bhalf8* wp8_ = (const bhalf8*)wp1;
            bhalf8 a0 = wp8_[0 * 64 + lane];
            bhalf8 a1 = wp8_[1 * 64 + lane];
            bhalf8 a2 = wp8_[2 * 64 + lane];
            bhalf8 a3 = wp8_[3 * 64 + lane];
            bhalf8 bb = *(const bhalf8*)&xin[(yy * 12 + xx) * 72 + q * 8];
#pragma unroll 1
            for (int p = 0; p < 18; ++p) {
                bhalf8 na0, na1, na2, na3, nbb;
                if (p < 17) {
                    int pn = p + 1;
                    na0 = wp8_[(pn * 4 + 0) * 64 + lane];
                    na1 = wp8_[(pn * 4 + 1) * 64 + lane];
                    na2 = wp8_[(pn * 4 + 2) * 64 + lane];
                    na3 = wp8_[(pn * 4 + 3) * 64 + lane];
                    int tap = pn >> 1, ch = pn & 1;
                    int dy = tap / 3, dx = tap - dy * 3;
                    nbb = *(const bhalf8*)&xin[((yy + dy) * 12 + xx + dx) * 72 + ch * 32 + q * 8];
                }
                acc1[0] = __builtin_amdgcn_mfma_f32_16x16x32_bf16(a0, bb, acc1[0], 0, 0, 0);
                acc1[1] = __builtin_amdgcn_mfma_f32_16x16x32_bf16(a1, bb, acc1[1], 0, 0, 0);
                acc1[2] = __builtin_amdgcn_mfma_f32_16x16x32_bf16(a2, bb, acc1[2], 0, 0, 0);
                acc1[3] = __builtin_amdgcn_mfma_f32_16x16x32_bf16(a3, bb, acc1[3], 0, 0, 0);
                a0 = na0; a1 = na1; a2 = na2; a3 = na3; bb = nbb;
            }
        }

        int iy = y0 - 1 + yy, ix = x0 - 1 + xx;
        bool ok1 = val && iy >= 0 && iy < H && ix >= 0 && ix < H;
        if (val) {
#pragma unroll
            for (int m = 0; m < 4; ++m) {
                ushort4 o = {0, 0, 0, 0};
                if (ok1) {
                    o.x = f2bf(fmaxf(acc1[m][0], 0.f));
                    o.y = f2bf(fmaxf(acc1[m][1], 0.f));
                    o.z = f2bf(fmaxf(acc1[m][2], 0.f));
                    o.w = f2bf(fmaxf(acc1[m][3], 0.f));
                }
                *(ushort4*)&ilds[px * 72 + m * 16 + q * 4] = o;
            }
        }
    }
    __syncthreads();

    // conv2: 8x8 output from ilds
    f32x4 acc[4];
#pragma unroll
    for (int m = 0; m < 4; ++m) acc[m] = (f32x4){0.f, 0.f, 0.f, 0.f};
    const bhalf8* w2 = (const bhalf8*)wp2;
    int sy = 2 * w + (n >> 3), sx = n & 7;

    bhalf8 a0 = w2[0 * 64 + lane];
    bhalf8 a1 = w2[1 * 64 + lane];
    bhalf8 a2 = w2[2 * 64 + lane];
    bhalf8 a3 = w2[3 * 64 + lane];
    bhalf8 bb = *(const bhalf8*)&ilds[(sy * 10 + sx) * 72 + q * 8];

#pragma unroll 1
    for (int p = 0; p < 18; ++p) {
        bhalf8 na0, na1, na2, na3, nbb;
        if (p < 17) {
            int pn = p + 1;
            na0 = w2[(pn * 4 + 0) * 64 + lane];
            na1 = w2[(pn * 4 + 1) * 64 + lane];
            na2 = w2[(pn * 4 + 2) * 64 + lane];
            na3 = w2[(pn * 4 + 3) * 64 + lane];
            int tap = pn >> 1, ch = pn & 1;
            int dy = tap / 3, dx = tap - dy * 3;
            nbb = *(const bhalf8*)&ilds[((sy + dy) * 10 + sx + dx) * 72 + ch * 32 + q * 8];
        }
        acc[0] = __builtin_amdgcn_mfma_f32_16x16x32_bf16(a0, bb, acc[0], 0, 0, 0);
        acc[1] = __builtin_amdgcn_mfma_f32_16x16x32_bf16(a1, bb, acc[1], 0, 0, 0);
        acc[2] = __builtin_amdgcn_mfma_f32_16x16x32_bf16(a2, bb, acc[2], 0, 0, 0);
        acc[3] = __builtin_amdgcn_mfma_f32_16x16x32_bf16(a3, bb, acc[3], 0, 0, 0);
        a0 = na0; a1 = na1; a2 = na2; a3 = na3; bb = nbb;
    }

    int gy = y0 + sy, gx = x0 + sx;
    if (gy < H && gx < H) {
        int base = (gy * H + gx) << 6;
#pragma unroll
        for (int m = 0; m < 4; ++m) {
            int oc0 = m * 16 + q * 4;
            ushort4 xr = *(const ushort4*)&xin[((sy + 2) * 12 + sx + 2) * 72 + oc0];
            float v0 = fmaxf(acc[m][0] + b2f(xr.x), 0.f);
            float v1 = fmaxf(acc[m][1] + b2f(xr.y), 0.f);
            float v2 = fmaxf(acc[m][2] + b2f(xr.z), 0.f);
            float v3 = fmaxf(acc[m][3] + b2f(xr.w), 0.f);
            if (final_) {
                int pix = gy * H + gx;
                outf[(oc0 + 0) * H * H + pix] = v0;
                outf[(oc0 + 1) * H * H + pix] = v1;
                outf[(oc0 + 2) * H * H + pix] = v2;
                outf[(oc0 + 3) * H * H + pix] = v3;
            } else {
                ushort4 o = { f2bf(v0), f2bf(v1), f2bf(v2), f2bf(v3) };
                chstore4(&outb[base + oc0], o);
            }
        }
    }
}

// ---------------------------------------------------------------------------
// Persistent megakernel: 8 phases, 7 grid barriers.
// ---------------------------------------------------------------------------
__global__ __launch_bounds__(256, 4) void gls_mega(
    const float* __restrict__ feats, const float* __restrict__ bev_emb,
    const float* __restrict__ conv1_w, const float* __restrict__ blk_w,
    const float* __restrict__ up_w, const float* __restrict__ means,
    const float* __restrict__ cov6, const float* __restrict__ opac,
    u16* __restrict__ wprep, float* __restrict__ params, int* __restrict__ cnts,
    u16* __restrict__ R0h, u16* __restrict__ X0h,
    u16* __restrict__ X1h, u16* __restrict__ X2h,
    u16* __restrict__ Qr0h, u16* __restrict__ Sh,
    u16* __restrict__ Uh, u16* __restrict__ Y1h,
    float* __restrict__ out, int* __restrict__ barmem, float* __restrict__ sacc)
{
    __shared__ __align__(16) char smem[36352];
    int bid = blockIdx.x;
    int tid = threadIdx.x;
    int* leaf = barmem;
    int* root = barmem + 512;
    int* flag = barmem + 513;
    int ph = 0;

    // ---- P0: parallel splat precompute (16 blocks) ----
    if (bid < 16) {
        int item = bid * 256 + tid;
        int s = item >> 11, g = item & 2047;
        float mx = means[g * 3 + 0], my = means[g * 3 + 1], mz = means[g * 3 + 2];
        float op = opac[g * 2 + s];
        bool mask = (mx >= -50.f && mx <= 50.f && my >= -50.f && my <= 50.f &&
                     mz >= -4.f && mz <= 4.f && op > 0.05f);
        float Hs = (float)(100 << s), sh = (float)(1 << s);
        float u = 0.f, v = 0.f, A = 0.f, B = 0.f, C = 0.f, pthr = 0.f;
        float rx = -1.f, ry = -1.f;
        if (mask) {
            u = -sh * my + 0.5f * Hs;
            v = -sh * mx + 0.5f * Hs;
            float a = sh * sh * cov6[g * 6 + 3] + 0.3f;
            float c = sh * sh * cov6[g * 6 + 0] + 0.3f;
            float bb = sh * sh * cov6[g * 6 + 1];
            float det = fmaxf(a * c - bb * bb, 1e-8f);
            float t = logf(255.f * op);
            A = c / det; B = -bb / det; C = a / det;
            pthr = -t;
            rx = sqrtf(2.f * t * a); ry = sqrtf(2.f * t * c);
        }
        float* Q = params + (s * G_N + g) * PSTR;
        cstore8(&Q[0], u, v);
        cstore8(&Q[2], A, B);
        cstore8(&Q[4], C, op);
        cstore8(&Q[6], pthr, __int_as_float(g));
        cstore8(&Q[8], rx, ry);
        unsigned long long bal = __ballot(mask);
        if ((tid & 63) == 0) atomicAdd(&cnts[s], __popcll(bal));
    }
    gbar(leaf, root, flag, ++ph);

    // ---- P1: render (0..793) || weight repack (794..991) ----
    if (bid < 794) {
        render_tile(bid, params, feats, R0h, Qr0h, smem);
    } else if (bid < 992) {
        int rb = bid - 794;
        int p = rb % 18, c = rb / 18;
        const float* src;
        if (c == 0) src = conv1_w;
        else if (c <= 4) src = blk_w + (c - 1) * WC;
        else if (c == 5) src = conv1_w + WC;
        else if (c == 6) src = up_w;
        else src = blk_w + (c - 3) * WC;
        int tap = p >> 1;
        int m = tid >> 6, lane = tid & 63;
        int oc = m * 16 + (lane & 15);
        int ci0 = (p & 1) * 32 + (lane >> 4) * 8;
        u16 v[8];
#pragma unroll
        for (int j = 0; j < 8; ++j)
            v[j] = f2bf(src[(oc * 64 + ci0 + j) * 9 + tap]);
        u16* dst = wprep + ((c * 18 + p) * 4 + m) * 64 * 8 + lane * 8;
        chstore4(dst, (ushort4){v[0], v[1], v[2], v[3]});
        chstore4(dst + 4, (ushort4){v[4], v[5], v[6], v[7]});
    }
    gbar(leaf, root, flag, ++ph);

    // ---- P2: c0 (H100, +bev_emb) ----
    if (bid < 169)
        conv_tile(bid, 100, R0h, wprep + 0 * WC, bev_emb, X0h, 0, 0, nullptr, smem);
    gbar(leaf, root, flag, ++ph);

    // ---- P3: bb1 (H100) || c5 tiles 0..311 ----
    if (bid < 169)
        bb_tile(bid, 100, X0h, wprep + 1 * WC, wprep + 2 * WC, X1h,
                nullptr, 0, 0, nullptr, nullptr, smem);
    else if (bid < 481)
        conv_tile(bid - 169, 200, Qr0h, wprep + 5 * WC, nullptr, Sh, 0, 0, nullptr, smem);
    gbar(leaf, root, flag, ++ph);

    // ---- P4: bb2 (H100) || c5 tiles 312..624 ----
    if (bid < 169)
        bb_tile(bid, 100, X1h, wprep + 3 * WC, wprep + 4 * WC, X2h,
                nullptr, 0, 0, nullptr, nullptr, smem);
    else if (bid < 482)
        conv_tile(312 + bid - 169, 200, Qr0h, wprep + 5 * WC, nullptr, Sh, 0, 0, nullptr, smem);
    gbar(leaf, root, flag, ++ph);

    // ---- P5: upconv (LDS bilinear) + instance-norm stats ----
    if (bid < 625)
        conv_tile(bid, 200, X2h, wprep + 6 * WC, nullptr, Uh, 1, 1, sacc, smem);
    gbar(leaf, root, flag, ++ph);

    // ---- P6: fused bb with instance-norm + skip staging ----
    if (bid < 625)
        bb_tile(bid, 200, Uh, wprep + 7 * WC, wprep + 8 * WC, Y1h,
                nullptr, 0, 1, Sh, sacc, smem);
    gbar(leaf, root, flag, ++ph);

    // ---- P7: fused bb, final epilogue writes d_out (f32 NCHW) ----
    if (bid == 0 && threadIdx.x == 0)
        out[2560000] = (float)(iload(&cnts[0]) + iload(&cnts[1]));
    if (bid < 625)
        bb_tile(bid, 200, Y1h, wprep + 9 * WC, wprep + 10 * WC, nullptr,
                out, 1, 0, nullptr, nullptr, smem);
}

// ---------------------------------------------------------------------------
extern "C" void kernel_launch(void* const* d_in, const int* in_sizes, int n_in,
                              void* d_out, int out_size, void* d_ws, size_t ws_size,
                              hipStream_t stream)
{
    const float* feats   = (const float*)d_in[0];
    const float* means   = (const float*)d_in[1];
    const float* cov6    = (const float*)d_in[2];
    const float* opac    = (const float*)d_in[3];
    const float* bev_emb = (const float*)d_in[4];
    const float* conv1_w = (const float*)d_in[5];
    const float* blk_w   = (const float*)d_in[6];
    const float* up_w    = (const float*)d_in[7];
    float* out = (float*)d_out;
    float* ws = (float*)d_ws;

    float* P      = ws;                          // 49152 floats
    int*   cnts   = (int*)(ws + 49152);          // 2 ints
    int*   barmem = (int*)(ws + 49280);          // 520 ints
    float* sacc   = ws + 49856;                  // 128 floats -> ends 49984
    u16*   wprep  = (u16*)(ws + 50176);          // 11*36864 u16

    u16* R0h  = (u16*)(ws + 262144);             // H100 bf16 HWC
    u16* X0h  = (u16*)(ws + 589824);
    u16* X1h  = (u16*)(ws + 917504);
    u16* X2h  = (u16*)(ws + 1245184);
    u16* Qr0h = (u16*)(ws + 1572864);            // H200 bf16 HWC
    u16* Sh   = (u16*)(ws + 2883584);
    u16* Uh   = (u16*)(ws + 4194304);
    u16* Y1h  = (u16*)(ws + 5505024);

    hipMemsetAsync(cnts, 0, (49984 - 49152) * 4, stream);
    gls_mega<<<NBLK, 256, 0, stream>>>(feats, bev_emb, conv1_w, blk_w, up_w,
                                       means, cov6, opac, wprep, P, cnts,
                                       R0h, X0h, X1h, X2h, Qr0h, Sh, Uh, Y1h,
                                       out, barmem, sacc);
    (void)in_sizes; (void)n_in; (void)out_size; (void)ws_size;
}